// Round 7
// baseline (453.904 us; speedup 1.0000x reference)
//
#include <hip/hip_runtime.h>
#include <cstdint>
#include <cstddef>

typedef __attribute__((ext_vector_type(8))) short bf16x8;
typedef __attribute__((ext_vector_type(8))) unsigned short us8;
typedef __attribute__((ext_vector_type(4))) float f32x4;

#define TSEQ 2048

__device__ __forceinline__ unsigned short f2bf(float f) {
  union { float f; uint32_t u; } v; v.f = f;
  uint32_t u = v.u;
  uint32_t r = (u + 0x7FFFu + ((u >> 16) & 1u)) >> 16;
  return (unsigned short)r;
}
__device__ __forceinline__ unsigned short f2bf_trunc(float f) {
  union { float f; uint32_t u; } v; v.f = f;
  return (unsigned short)(v.u >> 16);
}
__device__ __forceinline__ float bf2f(unsigned short h) {
  union { uint32_t u; float f; } v; v.u = ((uint32_t)h) << 16;
  return v.f;
}

__device__ __forceinline__ void async16(const void* g, void* l) {
  __builtin_amdgcn_global_load_lds(
      (const __attribute__((address_space(1))) unsigned int*)g,
      (__attribute__((address_space(3))) unsigned int*)l,
      16, 0, 0);
}

// ---------------------------------------------------------------------------
// RoPE cos/sin table: tbl[t*64 + j] = (cos(t*theta_j), sin(t*theta_j)),
// theta_j = 10000^(-2j/128). 2048*64 entries = 1 MiB. Computed once with
// precise sincosf; the GEMM epilogue then just loads (Appendix-B trig-table).
// ---------------------------------------------------------------------------
__global__ __launch_bounds__(256) void rope_table(float2* __restrict__ tbl)
{
  const int idx = blockIdx.x * 256 + threadIdx.x;  // 0..131071
  const int t = idx >> 6;
  const int j = idx & 63;
  // theta_j = 2^(-2j * log2(10000)/128), 2*log2(10000)/128 = 0.20762050593
  float sn, cs;
  sincosf((float)t * exp2f((float)j * -0.2076205059273837f), &sn, &cs);
  tbl[idx] = make_float2(cs, sn);
}

// ---------------------------------------------------------------------------
// x (fp32) -> xb (bf16), 16 elems/thread
// ---------------------------------------------------------------------------
__global__ __launch_bounds__(256) void cvt_x(
    const float* __restrict__ in, unsigned short* __restrict__ out)
{
  const size_t i = ((size_t)blockIdx.x * 256 + threadIdx.x) * 16;
  f32x4 a0 = *(const f32x4*)(in + i);
  f32x4 a1 = *(const f32x4*)(in + i + 4);
  f32x4 a2 = *(const f32x4*)(in + i + 8);
  f32x4 a3 = *(const f32x4*)(in + i + 12);
  us8 lo, hi;
#pragma unroll
  for (int j = 0; j < 4; j++) {
    lo[j] = f2bf(a0[j]); lo[j + 4] = f2bf(a1[j]);
    hi[j] = f2bf(a2[j]); hi[j + 4] = f2bf(a3[j]);
  }
  *(us8*)(out + i) = lo;
  *(us8*)(out + i + 8) = hi;
}

// ---------------------------------------------------------------------------
// out(C x R bf16) = transpose of in(R x C fp32)
// ---------------------------------------------------------------------------
__global__ __launch_bounds__(256) void transpose_w(
    const float* __restrict__ in, unsigned short* __restrict__ out,
    int R, int C)
{
  __shared__ unsigned short tile[32][33];
  const int bx = blockIdx.x * 32;
  const int by = blockIdx.y * 32;
  const int tx = threadIdx.x & 31;
  const int ty = threadIdx.x >> 5;
#pragma unroll
  for (int r = ty; r < 32; r += 8)
    tile[r][tx] = f2bf(in[(size_t)(by + r) * C + bx + tx]);
  __syncthreads();
#pragma unroll
  for (int r = ty; r < 32; r += 8)
    out[(size_t)(bx + r) * R + by + tx] = tile[tx][r];
}

// ---------------------------------------------------------------------------
// 128x128 BK=64 gemm (m97-structure, ~838 TF — known-good workhorse).
// MODE 1: fp32 output (proj). MODE 2: bf16 output with fused RoPE on
// cols < 4096 (q,k) and 1/sqrt(128) fold on cols < 2048 (q).
// Rope pair partner (col^1) lives in lane^1 -> __shfl_xor; cos/sin from tbl.
// ---------------------------------------------------------------------------
template <int MODE>
__global__ __launch_bounds__(256) void gemm_bt(
    const unsigned short* __restrict__ A,
    const unsigned short* __restrict__ Bt,
    void* __restrict__ Cv,
    int M, int N, int K, int ldc,
    const float2* __restrict__ tbl)
{
  __shared__ unsigned short As[2][128 * 32];
  __shared__ unsigned short Bs[2][128 * 32];
  const int tid  = threadIdx.x;
  const int lane = tid & 63;
  const int w    = tid >> 6;
  const int m0   = blockIdx.y * 128;
  const int n0   = blockIdx.x * 128;
  const int wm   = (w & 1) * 64;
  const int wn   = (w >> 1) * 64;

  const int srow = lane >> 2;
  const int scol = (lane & 3) * 8;
  const unsigned short* ga0 = A  + (size_t)(m0 + w * 16 + srow) * K + scol;
  const unsigned short* ga1 = ga0 + (size_t)64 * K;
  const unsigned short* gb0 = Bt + (size_t)(n0 + w * 16 + srow) * K + scol;
  const unsigned short* gb1 = gb0 + (size_t)64 * K;

  f32x4 acc[4][4];
#pragma unroll
  for (int i = 0; i < 4; i++)
#pragma unroll
    for (int j = 0; j < 4; j++) acc[i][j] = (f32x4){0.f, 0.f, 0.f, 0.f};

  const int frow = lane & 15;
  const int fcol = (lane >> 4) * 8;

  for (int kt = 0; kt < K; kt += 64) {
    __syncthreads();
    async16(ga0 + kt,      &As[0][w * 512]);
    async16(ga1 + kt,      &As[0][(4 + w) * 512]);
    async16(ga0 + kt + 32, &As[1][w * 512]);
    async16(ga1 + kt + 32, &As[1][(4 + w) * 512]);
    async16(gb0 + kt,      &Bs[0][w * 512]);
    async16(gb1 + kt,      &Bs[0][(4 + w) * 512]);
    async16(gb0 + kt + 32, &Bs[1][w * 512]);
    async16(gb1 + kt + 32, &Bs[1][(4 + w) * 512]);
    __syncthreads();

#pragma unroll
    for (int h = 0; h < 2; h++) {
      bf16x8 af[4], bfr[4];
#pragma unroll
      for (int i = 0; i < 4; i++)
        af[i] = *(const bf16x8*)&As[h][(wm + i * 16 + frow) * 32 + fcol];
#pragma unroll
      for (int i = 0; i < 4; i++)
        bfr[i] = *(const bf16x8*)&Bs[h][(wn + i * 16 + frow) * 32 + fcol];
#pragma unroll
      for (int mi = 0; mi < 4; mi++)
#pragma unroll
        for (int ni = 0; ni < 4; ni++)
          acc[mi][ni] = __builtin_amdgcn_mfma_f32_16x16x32_bf16(
              af[mi], bfr[ni], acc[mi][ni], 0, 0, 0);
    }
  }

  // C/D layout (m89-verified): col = lane&15, row = (lane>>4)*4 + reg
  const int crow0 = m0 + wm + (lane >> 4) * 4;
  const int ccol0 = n0 + wn + (lane & 15);
  if (MODE == 1) {
    float* Cf = (float*)Cv;
#pragma unroll
    for (int mi = 0; mi < 4; mi++)
#pragma unroll
      for (int i = 0; i < 4; i++) {
        const int row = crow0 + mi * 16 + i;
#pragma unroll
        for (int ni = 0; ni < 4; ni++)
          Cf[(size_t)row * ldc + ccol0 + ni * 16] = acc[mi][ni][i];
      }
  } else {
    unsigned short* Cb = (unsigned short*)Cv;
    const bool doRope = (n0 < 4096);            // block-uniform (q,k cols)
    const float sc = (n0 < 2048) ? 0.08838834764831845f : 1.0f;  // q scale
    const int odd = lane & 1;
#pragma unroll
    for (int mi = 0; mi < 4; mi++)
#pragma unroll
      for (int i = 0; i < 4; i++) {
        const int row = crow0 + mi * 16 + i;
        if (doRope) {
          const size_t tof = (size_t)(row & (TSEQ - 1)) * 64;
          float2 cs[4];
#pragma unroll
          for (int ni = 0; ni < 4; ni++)
            cs[ni] = tbl[tof + (((ccol0 + ni * 16) & 126) >> 1)];
#pragma unroll
          for (int ni = 0; ni < 4; ni++) {
            const float v = acc[mi][ni][i];
            const float p = __shfl_xor(v, 1);
            const float o = (odd ? (v * cs[ni].x + p * cs[ni].y)
                                 : (v * cs[ni].x - p * cs[ni].y)) * sc;
            Cb[(size_t)row * ldc + ccol0 + ni * 16] = f2bf(o);
          }
        } else {
#pragma unroll
          for (int ni = 0; ni < 4; ni++)
            Cb[(size_t)row * ldc + ccol0 + ni * 16] = f2bf(acc[mi][ni][i]);
        }
      }
  }
}

// ---------------------------------------------------------------------------
// Repack V: qkv cols [4096,6144) -> Vtg[b][h][d=128][t=2048]
// ---------------------------------------------------------------------------
__global__ __launch_bounds__(256) void repack_v(
    const unsigned short* __restrict__ qkv, unsigned short* __restrict__ Vtg)
{
  __shared__ unsigned short tile[32][33];
  const int tt = blockIdx.x * 32;
  const int dd = blockIdx.y * 32;
  const int bh = blockIdx.z;
  const int b  = bh >> 4, h = bh & 15;
  const int tx = threadIdx.x & 31;
  const int ty = threadIdx.x >> 5;
#pragma unroll
  for (int r = ty; r < 32; r += 8)
    tile[r][tx] = qkv[(size_t)(b * TSEQ + tt + r) * 6144 + 4096 + h * 128 + dd + tx];
  __syncthreads();
#pragma unroll
  for (int r = ty; r < 32; r += 8)
    Vtg[(size_t)bh * 262144 + (size_t)(dd + r) * TSEQ + tt + tx] = tile[tx][r];
}

// ---------------------------------------------------------------------------
// Flash attention. block = (b,h,128 q-rows), 4 waves x 32 q-rows, K-chunk 64.
// Round-7 changes:
//  - drop ones-column row-sum: denominator now accumulated in-register from
//    the SAME truncated-bf16 P values (in-lane sum over ct, then 4-step
//    shfl_xor over the 16-lane group) -> numerically identical to the
//    ones-MFMA. Saves 16 Vs rows + 4 MFMA + 2 ds_reads per wave/iter.
//  - LDS 56.6KB -> 54272B = exactly 3 blocks/CU (was 2): +50% resident
//    waves for latency hiding (T14's win showed latency sensitivity).
//  - keeps T14 reg-prefetch + T5 setprio from round 6.
// ---------------------------------------------------------------------------
__global__ __launch_bounds__(256) void attn(
    const unsigned short* __restrict__ qkv,  // (4096,6144) rope'd, q pre-scaled
    const unsigned short* __restrict__ Vtg,  // (32,128,2048)
    unsigned short* __restrict__ y)          // (4096,2048)
{
  __shared__ unsigned short Ks[64 * 136];
  __shared__ unsigned short Vs[128 * 72];
  __shared__ unsigned short Ps[4][32 * 72];

  const int tid  = threadIdx.x;
  const int lane = tid & 63;
  const int w    = tid >> 6;
  const int q0   = blockIdx.x * 128;
  const int h    = blockIdx.y;
  const int b    = blockIdx.z;
  const int bh   = b * 16 + h;
  const int quad = lane >> 4;
  const int l15  = lane & 15;
  const int kq   = quad * 8;

  bf16x8 qa[2][4];
#pragma unroll
  for (int mt = 0; mt < 2; mt++) {
    const unsigned short* gQ =
        qkv + (size_t)(b * TSEQ + q0 + w * 32 + mt * 16 + l15) * 6144 + h * 128 + kq;
#pragma unroll
    for (int dc = 0; dc < 4; dc++) qa[mt][dc] = *(const bf16x8*)(gQ + dc * 32);
  }

  f32x4 ot[2][8];
#pragma unroll
  for (int mt = 0; mt < 2; mt++)
#pragma unroll
    for (int nt = 0; nt < 8; nt++) ot[mt][nt] = (f32x4){0.f, 0.f, 0.f, 0.f};
  float rs[2][4];
#pragma unroll
  for (int mt = 0; mt < 2; mt++)
#pragma unroll
    for (int i = 0; i < 4; i++) rs[mt][i] = 0.f;

  const int krow = tid >> 2;
  const int kd   = (tid & 3) * 32;
  const unsigned short* gK = qkv + (size_t)(b * TSEQ) * 6144 + 2048 + h * 128 + kd;
  const int vd = tid >> 1;
  const int vc = (tid & 1) * 32;
  const unsigned short* gVt = Vtg + (size_t)bh * 262144 + (size_t)vd * TSEQ + vc;

  // T14 prologue: chunk 0 -> regs
  us8 kreg[4], vreg[4];
  {
    const unsigned short* pk = gK + (size_t)krow * 6144;
#pragma unroll
    for (int j = 0; j < 4; j++) kreg[j] = *(const us8*)(pk + j * 8);
#pragma unroll
    for (int j = 0; j < 4; j++) vreg[j] = *(const us8*)(gVt + j * 8);
  }

  for (int kb = 0; kb < TSEQ; kb += 64) {
    __syncthreads();
    // write the prefetched chunk to LDS
#pragma unroll
    for (int j = 0; j < 4; j++)
      *(us8*)&Ks[krow * 136 + kd + j * 8] = kreg[j];
#pragma unroll
    for (int j = 0; j < 4; j++)
      *(us8*)&Vs[vd * 72 + vc + j * 8] = vreg[j];
    __syncthreads();

    // issue next chunk's global loads; they drain under the MFMA/exp phase
    if (kb + 64 < TSEQ) {
      const unsigned short* pk = gK + (size_t)(kb + 64 + krow) * 6144;
#pragma unroll
      for (int j = 0; j < 4; j++) kreg[j] = *(const us8*)(pk + j * 8);
      const unsigned short* pv = gVt + kb + 64;
#pragma unroll
      for (int j = 0; j < 4; j++) vreg[j] = *(const us8*)(pv + j * 8);
    }

    f32x4 s[2][4];
#pragma unroll
    for (int mt = 0; mt < 2; mt++)
#pragma unroll
      for (int ct = 0; ct < 4; ct++) s[mt][ct] = (f32x4){0.f, 0.f, 0.f, 0.f};
    __builtin_amdgcn_s_setprio(1);
#pragma unroll
    for (int dc = 0; dc < 4; dc++) {
#pragma unroll
      for (int ct = 0; ct < 4; ct++) {
        bf16x8 kf = *(const bf16x8*)&Ks[(ct * 16 + l15) * 136 + dc * 32 + kq];
        s[0][ct] = __builtin_amdgcn_mfma_f32_16x16x32_bf16(qa[0][dc], kf, s[0][ct], 0, 0, 0);
        s[1][ct] = __builtin_amdgcn_mfma_f32_16x16x32_bf16(qa[1][dc], kf, s[1][ct], 0, 0, 0);
      }
    }
    __builtin_amdgcn_s_setprio(0);

    unsigned short* pw = &Ps[w][0];
    float t8[2][4];
#pragma unroll
    for (int mt = 0; mt < 2; mt++)
#pragma unroll
      for (int i = 0; i < 4; i++) t8[mt][i] = 0.f;
#pragma unroll
    for (int mt = 0; mt < 2; mt++)
#pragma unroll
      for (int ct = 0; ct < 4; ct++)
#pragma unroll
        for (int i = 0; i < 4; i++) {
          const unsigned short us = f2bf_trunc(__expf(fminf(s[mt][ct][i], 30.f)));
          pw[(mt * 16 + quad * 4 + i) * 72 + ct * 16 + l15] = us;
          t8[mt][i] += bf2f(us);
        }
    // cross-lane row-sum over the 16-lane group (cols), add into running sums
#pragma unroll
    for (int mt = 0; mt < 2; mt++)
#pragma unroll
      for (int i = 0; i < 4; i++) {
        float v = t8[mt][i];
        v += __shfl_xor(v, 1);
        v += __shfl_xor(v, 2);
        v += __shfl_xor(v, 4);
        v += __shfl_xor(v, 8);
        rs[mt][i] += v;
      }

    __asm__ volatile("s_waitcnt lgkmcnt(0)" ::: "memory");

    __builtin_amdgcn_s_setprio(1);
#pragma unroll
    for (int kc = 0; kc < 2; kc++) {
      bf16x8 pa0 = *(const bf16x8*)&pw[(l15) * 72 + kc * 32 + kq];
      bf16x8 pa1 = *(const bf16x8*)&pw[(16 + l15) * 72 + kc * 32 + kq];
#pragma unroll
      for (int nt = 0; nt < 8; nt++) {
        bf16x8 vb = *(const bf16x8*)&Vs[(nt * 16 + l15) * 72 + kc * 32 + kq];
        ot[0][nt] = __builtin_amdgcn_mfma_f32_16x16x32_bf16(pa0, vb, ot[0][nt], 0, 0, 0);
        ot[1][nt] = __builtin_amdgcn_mfma_f32_16x16x32_bf16(pa1, vb, ot[1][nt], 0, 0, 0);
      }
    }
    __builtin_amdgcn_s_setprio(0);
  }

#pragma unroll
  for (int mt = 0; mt < 2; mt++) {
    unsigned short* gy =
        y + (size_t)(b * TSEQ + q0 + w * 32 + mt * 16 + quad * 4) * 2048 + h * 128 + l15;
#pragma unroll
    for (int i = 0; i < 4; i++) {
      const float inv = 1.0f / rs[mt][i];   // lane-local row sum
#pragma unroll
      for (int nt = 0; nt < 8; nt++)
        gy[(size_t)i * 2048 + nt * 16] = f2bf(ot[mt][nt][i] * inv);
    }
  }
}

// ---------------------------------------------------------------------------
extern "C" void kernel_launch(void* const* d_in, const int* in_sizes, int n_in,
                              void* d_out, int out_size, void* d_ws, size_t ws_size,
                              hipStream_t stream)
{
  const float* x      = (const float*)d_in[0];
  const float* w_attn = (const float*)d_in[1];
  const float* w_proj = (const float*)d_in[2];

  if (ws_size < 67108864u) return;

  char* ws = (char*)d_ws;
  unsigned short* qkv = (unsigned short*)(ws);              // 48 MiB
  unsigned short* xb  = (unsigned short*)(ws + 50331648);   // 16 MiB (then y)
  unsigned short* y   = xb;
  unsigned short* wT2 = (unsigned short*)(ws);              // 8 MiB, after attn
  unsigned short* wTa = (unsigned short*)d_out;             // 24 MiB scratch
  float2* tbl = (float2*)((char*)d_out + 25165824);         // 1 MiB scratch
  unsigned short* Vtg = (unsigned short*)d_out;             // 16 MiB scratch (after gemm)

  transpose_w<<<dim3(192, 64), 256, 0, stream>>>(w_attn, wTa, 2048, 6144);
  rope_table<<<dim3(512), 256, 0, stream>>>(tbl);
  cvt_x<<<dim3(2048), 256, 0, stream>>>(x, xb);
  // QKV gemm with fused RoPE + q-scale
  gemm_bt<2><<<dim3(48, 32), 256, 0, stream>>>(xb, wTa, (void*)qkv, 4096, 6144, 2048, 6144, tbl);
  repack_v<<<dim3(64, 4, 32), 256, 0, stream>>>(qkv, Vtg);
  attn<<<dim3(16, 16, 2), 256, 0, stream>>>(qkv, Vtg, y);
  transpose_w<<<dim3(64, 64), 256, 0, stream>>>(w_proj, wT2, 2048, 2048);
  gemm_bt<1><<<dim3(16, 32), 256, 0, stream>>>(y, wT2, d_out, 4096, 2048, 2048, 2048, nullptr);
}

// Round 8
// 430.934 us; speedup vs baseline: 1.0533x; 1.0533x over previous
//
#include <hip/hip_runtime.h>
#include <cstdint>
#include <cstddef>

typedef __attribute__((ext_vector_type(8))) short bf16x8;
typedef __attribute__((ext_vector_type(8))) unsigned short us8;
typedef __attribute__((ext_vector_type(4))) float f32x4;

#define TSEQ 2048

__device__ __forceinline__ unsigned short f2bf(float f) {
  union { float f; uint32_t u; } v; v.f = f;
  uint32_t u = v.u;
  uint32_t r = (u + 0x7FFFu + ((u >> 16) & 1u)) >> 16;
  return (unsigned short)r;
}
__device__ __forceinline__ unsigned short f2bf_trunc(float f) {
  union { float f; uint32_t u; } v; v.f = f;
  return (unsigned short)(v.u >> 16);
}
__device__ __forceinline__ float bf2f(unsigned short h) {
  union { uint32_t u; float f; } v; v.u = ((uint32_t)h) << 16;
  return v.f;
}

__device__ __forceinline__ void async16(const void* g, void* l) {
  __builtin_amdgcn_global_load_lds(
      (const __attribute__((address_space(1))) unsigned int*)g,
      (__attribute__((address_space(3))) unsigned int*)l,
      16, 0, 0);
}

// ---------------------------------------------------------------------------
// x (fp32) -> xb (bf16), 16 elems/thread
// ---------------------------------------------------------------------------
__global__ __launch_bounds__(256) void cvt_x(
    const float* __restrict__ in, unsigned short* __restrict__ out)
{
  const size_t i = ((size_t)blockIdx.x * 256 + threadIdx.x) * 16;
  f32x4 a0 = *(const f32x4*)(in + i);
  f32x4 a1 = *(const f32x4*)(in + i + 4);
  f32x4 a2 = *(const f32x4*)(in + i + 8);
  f32x4 a3 = *(const f32x4*)(in + i + 12);
  us8 lo, hi;
#pragma unroll
  for (int j = 0; j < 4; j++) {
    lo[j] = f2bf(a0[j]); lo[j + 4] = f2bf(a1[j]);
    hi[j] = f2bf(a2[j]); hi[j + 4] = f2bf(a3[j]);
  }
  *(us8*)(out + i) = lo;
  *(us8*)(out + i + 8) = hi;
}

// ---------------------------------------------------------------------------
// out(C x R bf16) = transpose of in(R x C fp32)
// ---------------------------------------------------------------------------
__global__ __launch_bounds__(256) void transpose_w(
    const float* __restrict__ in, unsigned short* __restrict__ out,
    int R, int C)
{
  __shared__ unsigned short tile[32][33];
  const int bx = blockIdx.x * 32;
  const int by = blockIdx.y * 32;
  const int tx = threadIdx.x & 31;
  const int ty = threadIdx.x >> 5;
#pragma unroll
  for (int r = ty; r < 32; r += 8)
    tile[r][tx] = f2bf(in[(size_t)(by + r) * C + bx + tx]);
  __syncthreads();
#pragma unroll
  for (int r = ty; r < 32; r += 8)
    out[(size_t)(bx + r) * R + by + tx] = tile[tx][r];
}

// ---------------------------------------------------------------------------
// 128x128 BK=64 gemm (m97-structure, ~838 TF known-good; r7's fused-RoPE
// epilogue cost 6->5 waves/SIMD occupancy (VGPR 76->88) and +35us — reverted).
// ---------------------------------------------------------------------------
template <int CF32>
__global__ __launch_bounds__(256) void gemm_bt(
    const unsigned short* __restrict__ A,
    const unsigned short* __restrict__ Bt,
    void* __restrict__ Cv,
    int M, int N, int K, int ldc)
{
  __shared__ unsigned short As[2][128 * 32];
  __shared__ unsigned short Bs[2][128 * 32];
  const int tid  = threadIdx.x;
  const int lane = tid & 63;
  const int w    = tid >> 6;
  const int m0   = blockIdx.y * 128;
  const int n0   = blockIdx.x * 128;
  const int wm   = (w & 1) * 64;
  const int wn   = (w >> 1) * 64;

  const int srow = lane >> 2;
  const int scol = (lane & 3) * 8;
  const unsigned short* ga0 = A  + (size_t)(m0 + w * 16 + srow) * K + scol;
  const unsigned short* ga1 = ga0 + (size_t)64 * K;
  const unsigned short* gb0 = Bt + (size_t)(n0 + w * 16 + srow) * K + scol;
  const unsigned short* gb1 = gb0 + (size_t)64 * K;

  f32x4 acc[4][4];
#pragma unroll
  for (int i = 0; i < 4; i++)
#pragma unroll
    for (int j = 0; j < 4; j++) acc[i][j] = (f32x4){0.f, 0.f, 0.f, 0.f};

  const int frow = lane & 15;
  const int fcol = (lane >> 4) * 8;

  for (int kt = 0; kt < K; kt += 64) {
    __syncthreads();
    async16(ga0 + kt,      &As[0][w * 512]);
    async16(ga1 + kt,      &As[0][(4 + w) * 512]);
    async16(ga0 + kt + 32, &As[1][w * 512]);
    async16(ga1 + kt + 32, &As[1][(4 + w) * 512]);
    async16(gb0 + kt,      &Bs[0][w * 512]);
    async16(gb1 + kt,      &Bs[0][(4 + w) * 512]);
    async16(gb0 + kt + 32, &Bs[1][w * 512]);
    async16(gb1 + kt + 32, &Bs[1][(4 + w) * 512]);
    __syncthreads();

#pragma unroll
    for (int h = 0; h < 2; h++) {
      bf16x8 af[4], bfr[4];
#pragma unroll
      for (int i = 0; i < 4; i++)
        af[i] = *(const bf16x8*)&As[h][(wm + i * 16 + frow) * 32 + fcol];
#pragma unroll
      for (int i = 0; i < 4; i++)
        bfr[i] = *(const bf16x8*)&Bs[h][(wn + i * 16 + frow) * 32 + fcol];
#pragma unroll
      for (int mi = 0; mi < 4; mi++)
#pragma unroll
        for (int ni = 0; ni < 4; ni++)
          acc[mi][ni] = __builtin_amdgcn_mfma_f32_16x16x32_bf16(
              af[mi], bfr[ni], acc[mi][ni], 0, 0, 0);
    }
  }

  const int crow0 = m0 + wm + (lane >> 4) * 4;
  const int ccol0 = n0 + wn + (lane & 15);
  if (CF32) {
    float* Cf = (float*)Cv;
#pragma unroll
    for (int mi = 0; mi < 4; mi++)
#pragma unroll
      for (int i = 0; i < 4; i++) {
        const int row = crow0 + mi * 16 + i;
#pragma unroll
        for (int ni = 0; ni < 4; ni++)
          Cf[(size_t)row * ldc + ccol0 + ni * 16] = acc[mi][ni][i];
      }
  } else {
    unsigned short* Cb = (unsigned short*)Cv;
#pragma unroll
    for (int mi = 0; mi < 4; mi++)
#pragma unroll
      for (int i = 0; i < 4; i++) {
        const int row = crow0 + mi * 16 + i;
#pragma unroll
        for (int ni = 0; ni < 4; ni++)
          Cb[(size_t)row * ldc + ccol0 + ni * 16] = f2bf(acc[mi][ni][i]);
      }
  }
}

// ---------------------------------------------------------------------------
// RoPE in-place on qkv cols [0,4096); 1/sqrt(128) folded into q half.
// Round-8: vectorized to 16B/lane (4 pairs) — was 4B/lane (G13).
// ---------------------------------------------------------------------------
__global__ __launch_bounds__(256) void rope_qk(unsigned short* __restrict__ qkv)
{
  const int q   = blockIdx.x * 256 + threadIdx.x;  // 0 .. 2,097,151
  const int row = q >> 9;                          // 512 threads/row
  const int cb  = (q & 511) * 8;                   // col base in [0,4096)
  const int t   = row & (TSEQ - 1);
  const int hd  = cb & 127;
  const float sc = (cb < 2048) ? 0.08838834764831845f : 1.0f;
  unsigned short* base = qkv + (size_t)row * 6144 + cb;
  uint4 u = *(const uint4*)base;
  uint32_t wd[4] = {u.x, u.y, u.z, u.w};
#pragma unroll
  for (int k = 0; k < 4; k++) {
    const float theta = exp2f((float)(hd + 2 * k) * -0.1038102531f);
    float s, c;
    sincosf((float)t * theta, &s, &c);
    const float x0 = bf2f((unsigned short)(wd[k] & 0xffffu));
    const float x1 = bf2f((unsigned short)(wd[k] >> 16));
    const float o0 = (x0 * c - x1 * s) * sc;
    const float o1 = (x1 * c + x0 * s) * sc;
    wd[k] = (uint32_t)f2bf(o0) | ((uint32_t)f2bf(o1) << 16);
  }
  *(uint4*)base = make_uint4(wd[0], wd[1], wd[2], wd[3]);
}

// ---------------------------------------------------------------------------
// Repack V: qkv cols [4096,6144) -> Vtg[b][h][d=128][t=2048]
// Round-8: 16B global reads AND writes (was 2B/lane both sides); transpose
// via LDS (scalar writes 2-way-free; b128 row-contiguous reads).
// Block: 64 t x 128 d tile per (b,h). Grid (32, 32).
// ---------------------------------------------------------------------------
__global__ __launch_bounds__(256) void repack_v(
    const unsigned short* __restrict__ qkv, unsigned short* __restrict__ Vtg)
{
  __shared__ unsigned short tile[128][72];   // 18 KiB; 144B rows (16B-aligned)
  const int tt = blockIdx.x * 64;
  const int bh = blockIdx.y;
  const int b  = bh >> 4, h = bh & 15;

  {
    const int r  = threadIdx.x & 63;   // t within tile
    const int i0 = threadIdx.x >> 6;   // 0..3
    const unsigned short* src =
        qkv + (size_t)(b * TSEQ + tt + r) * 6144 + 4096 + h * 128;
#pragma unroll
    for (int i = i0; i < 16; i += 4) {
      us8 v = *(const us8*)(src + i * 8);
#pragma unroll
      for (int k = 0; k < 8; k++) tile[i * 8 + k][r] = v[k];
    }
  }
  __syncthreads();
  {
    unsigned short* dst = Vtg + (size_t)bh * 262144 + tt;
#pragma unroll
    for (int it = 0; it < 4; it++) {
      const int wdx = it * 256 + threadIdx.x;  // 0..1023
      const int d = wdx >> 3;
      const int j = (wdx & 7) * 8;
      us8 v = *(const us8*)&tile[d][j];
      *(us8*)(dst + (size_t)d * TSEQ + j) = v;
    }
  }
}

// ---------------------------------------------------------------------------
// Flash attention (r7 structure kept: T14 reg-prefetch, T5 setprio, in-reg
// row-sum, LDS 54272B = 3 blocks/CU).
// ---------------------------------------------------------------------------
__global__ __launch_bounds__(256) void attn(
    const unsigned short* __restrict__ qkv,  // (4096,6144) rope'd, q pre-scaled
    const unsigned short* __restrict__ Vtg,  // (32,128,2048)
    unsigned short* __restrict__ y)          // (4096,2048)
{
  __shared__ unsigned short Ks[64 * 136];
  __shared__ unsigned short Vs[128 * 72];
  __shared__ unsigned short Ps[4][32 * 72];

  const int tid  = threadIdx.x;
  const int lane = tid & 63;
  const int w    = tid >> 6;
  const int q0   = blockIdx.x * 128;
  const int h    = blockIdx.y;
  const int b    = blockIdx.z;
  const int bh   = b * 16 + h;
  const int quad = lane >> 4;
  const int l15  = lane & 15;
  const int kq   = quad * 8;

  bf16x8 qa[2][4];
#pragma unroll
  for (int mt = 0; mt < 2; mt++) {
    const unsigned short* gQ =
        qkv + (size_t)(b * TSEQ + q0 + w * 32 + mt * 16 + l15) * 6144 + h * 128 + kq;
#pragma unroll
    for (int dc = 0; dc < 4; dc++) qa[mt][dc] = *(const bf16x8*)(gQ + dc * 32);
  }

  f32x4 ot[2][8];
#pragma unroll
  for (int mt = 0; mt < 2; mt++)
#pragma unroll
    for (int nt = 0; nt < 8; nt++) ot[mt][nt] = (f32x4){0.f, 0.f, 0.f, 0.f};
  float rs[2][4];
#pragma unroll
  for (int mt = 0; mt < 2; mt++)
#pragma unroll
    for (int i = 0; i < 4; i++) rs[mt][i] = 0.f;

  const int krow = tid >> 2;
  const int kd   = (tid & 3) * 32;
  const unsigned short* gK = qkv + (size_t)(b * TSEQ) * 6144 + 2048 + h * 128 + kd;
  const int vd = tid >> 1;
  const int vc = (tid & 1) * 32;
  const unsigned short* gVt = Vtg + (size_t)bh * 262144 + (size_t)vd * TSEQ + vc;

  // T14 prologue: chunk 0 -> regs
  us8 kreg[4], vreg[4];
  {
    const unsigned short* pk = gK + (size_t)krow * 6144;
#pragma unroll
    for (int j = 0; j < 4; j++) kreg[j] = *(const us8*)(pk + j * 8);
#pragma unroll
    for (int j = 0; j < 4; j++) vreg[j] = *(const us8*)(gVt + j * 8);
  }

  for (int kb = 0; kb < TSEQ; kb += 64) {
    __syncthreads();
#pragma unroll
    for (int j = 0; j < 4; j++)
      *(us8*)&Ks[krow * 136 + kd + j * 8] = kreg[j];
#pragma unroll
    for (int j = 0; j < 4; j++)
      *(us8*)&Vs[vd * 72 + vc + j * 8] = vreg[j];
    __syncthreads();

    if (kb + 64 < TSEQ) {
      const unsigned short* pk = gK + (size_t)(kb + 64 + krow) * 6144;
#pragma unroll
      for (int j = 0; j < 4; j++) kreg[j] = *(const us8*)(pk + j * 8);
      const unsigned short* pv = gVt + kb + 64;
#pragma unroll
      for (int j = 0; j < 4; j++) vreg[j] = *(const us8*)(pv + j * 8);
    }

    f32x4 s[2][4];
#pragma unroll
    for (int mt = 0; mt < 2; mt++)
#pragma unroll
      for (int ct = 0; ct < 4; ct++) s[mt][ct] = (f32x4){0.f, 0.f, 0.f, 0.f};
    __builtin_amdgcn_s_setprio(1);
#pragma unroll
    for (int dc = 0; dc < 4; dc++) {
#pragma unroll
      for (int ct = 0; ct < 4; ct++) {
        bf16x8 kf = *(const bf16x8*)&Ks[(ct * 16 + l15) * 136 + dc * 32 + kq];
        s[0][ct] = __builtin_amdgcn_mfma_f32_16x16x32_bf16(qa[0][dc], kf, s[0][ct], 0, 0, 0);
        s[1][ct] = __builtin_amdgcn_mfma_f32_16x16x32_bf16(qa[1][dc], kf, s[1][ct], 0, 0, 0);
      }
    }
    __builtin_amdgcn_s_setprio(0);

    unsigned short* pw = &Ps[w][0];
    float t8[2][4];
#pragma unroll
    for (int mt = 0; mt < 2; mt++)
#pragma unroll
      for (int i = 0; i < 4; i++) t8[mt][i] = 0.f;
#pragma unroll
    for (int mt = 0; mt < 2; mt++)
#pragma unroll
      for (int ct = 0; ct < 4; ct++)
#pragma unroll
        for (int i = 0; i < 4; i++) {
          const unsigned short us = f2bf_trunc(__expf(fminf(s[mt][ct][i], 30.f)));
          pw[(mt * 16 + quad * 4 + i) * 72 + ct * 16 + l15] = us;
          t8[mt][i] += bf2f(us);
        }
#pragma unroll
    for (int mt = 0; mt < 2; mt++)
#pragma unroll
      for (int i = 0; i < 4; i++) {
        float v = t8[mt][i];
        v += __shfl_xor(v, 1);
        v += __shfl_xor(v, 2);
        v += __shfl_xor(v, 4);
        v += __shfl_xor(v, 8);
        rs[mt][i] += v;
      }

    __asm__ volatile("s_waitcnt lgkmcnt(0)" ::: "memory");

    __builtin_amdgcn_s_setprio(1);
#pragma unroll
    for (int kc = 0; kc < 2; kc++) {
      bf16x8 pa0 = *(const bf16x8*)&pw[(l15) * 72 + kc * 32 + kq];
      bf16x8 pa1 = *(const bf16x8*)&pw[(16 + l15) * 72 + kc * 32 + kq];
#pragma unroll
      for (int nt = 0; nt < 8; nt++) {
        bf16x8 vb = *(const bf16x8*)&Vs[(nt * 16 + l15) * 72 + kc * 32 + kq];
        ot[0][nt] = __builtin_amdgcn_mfma_f32_16x16x32_bf16(pa0, vb, ot[0][nt], 0, 0, 0);
        ot[1][nt] = __builtin_amdgcn_mfma_f32_16x16x32_bf16(pa1, vb, ot[1][nt], 0, 0, 0);
      }
    }
    __builtin_amdgcn_s_setprio(0);
  }

#pragma unroll
  for (int mt = 0; mt < 2; mt++) {
    unsigned short* gy =
        y + (size_t)(b * TSEQ + q0 + w * 32 + mt * 16 + quad * 4) * 2048 + h * 128 + l15;
#pragma unroll
    for (int i = 0; i < 4; i++) {
      const float inv = 1.0f / rs[mt][i];
#pragma unroll
      for (int nt = 0; nt < 8; nt++)
        gy[(size_t)i * 2048 + nt * 16] = f2bf(ot[mt][nt][i] * inv);
    }
  }
}

// ---------------------------------------------------------------------------
extern "C" void kernel_launch(void* const* d_in, const int* in_sizes, int n_in,
                              void* d_out, int out_size, void* d_ws, size_t ws_size,
                              hipStream_t stream)
{
  const float* x      = (const float*)d_in[0];
  const float* w_attn = (const float*)d_in[1];
  const float* w_proj = (const float*)d_in[2];

  if (ws_size < 67108864u) return;

  char* ws = (char*)d_ws;
  unsigned short* qkv = (unsigned short*)(ws);              // 48 MiB
  unsigned short* xb  = (unsigned short*)(ws + 50331648);   // 16 MiB (then y)
  unsigned short* y   = xb;
  unsigned short* wT2 = (unsigned short*)(ws);              // 8 MiB, after attn
  unsigned short* wTa = (unsigned short*)d_out;             // 24 MiB scratch
  unsigned short* Vtg = (unsigned short*)d_out;             // 16 MiB scratch

  transpose_w<<<dim3(192, 64), 256, 0, stream>>>(w_attn, wTa, 2048, 6144);
  cvt_x<<<dim3(2048), 256, 0, stream>>>(x, xb);
  gemm_bt<0><<<dim3(48, 32), 256, 0, stream>>>(xb, wTa, (void*)qkv, 4096, 6144, 2048, 6144);
  rope_qk<<<dim3(8192), 256, 0, stream>>>(qkv);
  repack_v<<<dim3(32, 32), 256, 0, stream>>>(qkv, Vtg);
  attn<<<dim3(16, 16, 2), 256, 0, stream>>>(qkv, Vtg, y);
  transpose_w<<<dim3(64, 64), 256, 0, stream>>>(w_proj, wT2, 2048, 2048);
  gemm_bt<1><<<dim3(16, 32), 256, 0, stream>>>(y, wT2, d_out, 4096, 2048, 2048, 2048);
}